// Round 7
// baseline (223.202 us; speedup 1.0000x reference)
//
#include <hip/hip_runtime.h>
#include <math.h>

typedef __attribute__((ext_vector_type(8))) short short8;
typedef __attribute__((ext_vector_type(4))) float f32x4;

constexpr int B   = 4;
constexpr int N   = 2304;
constexpr int DIM = 256;
constexpr int NH  = 8;
constexpr int DH  = 32;
constexpr int M   = B * N;          // 9216 rows
constexpr int SLOTS = 2336;         // N + 32: kept keys + pad + masked keys
constexpr int CST = SLOTS * DH;     // per-(b,h) compact K/V element count

// float -> bf16 round-to-nearest-even, truncation, and back
__device__ inline unsigned short f2bf(float f) {
    union { float f; unsigned u; } c; c.f = f;
    unsigned u = c.u;
    u += 0x7fffu + ((u >> 16) & 1u);
    return (unsigned short)(u >> 16);
}
__device__ inline unsigned short f2bf_trunc(float f) {
    union { float f; unsigned u; } c; c.f = f;
    return (unsigned short)(c.u >> 16);
}
__device__ inline float bf2f(unsigned short h) {
    union { unsigned u; float f; } c; c.u = ((unsigned)h) << 16;
    return c.f;
}

// ---- FragTile layouts: element (row r, contraction k) stored so an MFMA
// A/B-frag load (16 rows x 32 k) is ONE contiguous 1KB wave transaction.
__device__ inline size_t fo256(int r, int k) {   // [R x 256] tensors
    return ((size_t)((r >> 4) * 8 + (k >> 5)) << 9)
         + (size_t)(((((k & 31) >> 3) << 4) + (r & 15)) * 8 + (k & 7));
}
__device__ inline size_t foQK(int n, int d) {    // per-(b,h) [rows x 32]
    return ((size_t)(n >> 4) << 9)
         + (size_t)((((d >> 3) << 4) + (n & 15)) * 8 + (d & 7));
}
__device__ inline size_t foVTC(int d, int key) { // per-(b,h) [32 x SLOTS]
    return ((size_t)((d >> 4) * (SLOTS / 32) + (key >> 5)) << 9)
         + (size_t)(((((key & 31) >> 3) << 4) + (d & 15)) * 8 + (key & 7));
}

// ---------------- mask scan: kept/masked slot permutation per batch --------
// slot[n] = kept ? rank_kept(n) : Nkp + rank_masked(n).  Nkp = ceil32(Nc).
__global__ __launch_bounds__(256) void mask_scan(
    const float* __restrict__ mask, int* __restrict__ slotmap,
    int* __restrict__ ncp)
{
    __shared__ int wsum[4];
    int b = blockIdx.x, t = threadIdx.x;
    int wave = t >> 6, lane = t & 63;
    // pass 1: count kept
    int cnt = 0;
    for (int j = t; j < N; j += 256) cnt += (mask[(size_t)b * N + j] > 0.f);
    #pragma unroll
    for (int o = 32; o > 0; o >>= 1) cnt += __shfl_down(cnt, o, 64);
    if (lane == 0) wsum[wave] = cnt;
    __syncthreads();
    int Nc = wsum[0] + wsum[1] + wsum[2] + wsum[3];
    int Nkp = (Nc + 31) & ~31;
    if (t == 0) { ncp[b * 2] = Nc; ncp[b * 2 + 1] = Nkp; }
    // pass 2: ordered scan -> slots
    int baseK = 0;
    for (int j0 = 0; j0 < N; j0 += 256) {
        int j = j0 + t;
        bool keep = mask[(size_t)b * N + j] > 0.f;
        unsigned long long bal = __ballot(keep);
        int pos = __popcll(bal & ((1ull << lane) - 1ull));
        int wc  = __popcll(bal);
        __syncthreads();
        if (lane == 0) wsum[wave] = wc;
        __syncthreads();
        int wb = 0;
        for (int w = 0; w < wave; ++w) wb += wsum[w];
        int tot = wsum[0] + wsum[1] + wsum[2] + wsum[3];
        int keptBefore = baseK + wb + pos;
        slotmap[(size_t)b * N + j] = keep ? keptBefore : Nkp + (j - keptBefore);
        baseK += tot;
    }
}

// ---------------- LayerNorm -> hi/lo bf16 FragTile, one block per row ------
__global__ __launch_bounds__(256) void ln_kernel(
    const float* __restrict__ x, const float* __restrict__ g,
    const float* __restrict__ bta,
    unsigned short* __restrict__ xh, unsigned short* __restrict__ xl)
{
    __shared__ float red[4];
    int row = blockIdx.x;
    int t   = threadIdx.x;
    float v = x[(size_t)row * DIM + t];
    float s = v;
    #pragma unroll
    for (int o = 32; o > 0; o >>= 1) s += __shfl_down(s, o, 64);
    if ((t & 63) == 0) red[t >> 6] = s;
    __syncthreads();
    float mu = (red[0] + red[1] + red[2] + red[3]) * (1.0f / DIM);
    __syncthreads();
    float d  = v - mu;
    float s2 = d * d;
    #pragma unroll
    for (int o = 32; o > 0; o >>= 1) s2 += __shfl_down(s2, o, 64);
    if ((t & 63) == 0) red[t >> 6] = s2;
    __syncthreads();
    float var = (red[0] + red[1] + red[2] + red[3]) * (1.0f / DIM);
    float r   = rsqrtf(var + 1e-5f);
    float y   = d * r * g[t] + bta[t];
    unsigned short hh = f2bf(y);
    size_t o = fo256(row, t);
    xh[o] = hh;
    xl[o] = f2bf(y - bf2f(hh));
}

// ---------------- all 4 W (256x256 fp32) -> W^T hi/lo FragTile -------------
__global__ __launch_bounds__(256) void split_w(
    const float* __restrict__ Wq, const float* __restrict__ Wk,
    const float* __restrict__ Wv, const float* __restrict__ Wp,
    unsigned short* __restrict__ Wth, unsigned short* __restrict__ Wtl)
{
    int z = blockIdx.z;
    const float* W = (z == 0) ? Wq : (z == 1) ? Wk : (z == 2) ? Wv : Wp;
    unsigned short* oh = Wth + (size_t)z * DIM * DIM;
    unsigned short* ol = Wtl + (size_t)z * DIM * DIM;
    __shared__ float t[32][33];
    int tid = threadIdx.x;
    int tx = tid & 31, ty0 = tid >> 5;
    int n0 = blockIdx.x * 32, k0 = blockIdx.y * 32;
    for (int ty = ty0; ty < 32; ty += 8)
        t[ty][tx] = W[(size_t)(k0 + ty) * DIM + n0 + tx];
    __syncthreads();
    for (int nn = ty0; nn < 32; nn += 8) {
        float v = t[tx][nn];                 // = W[k0+tx][n0+nn] = Wt[n][k]
        unsigned short hh = f2bf(v);
        size_t o = fo256(n0 + nn, k0 + tx);
        oh[o] = hh;
        ol[o] = f2bf(v - bf2f(hh));
    }
}

// ---------------- fused Q/K/V split-bf16 MFMA GEMM -------------------------
// z=0: Q (full), z=1: K -> compact slots, z=2: V^T -> compact slots.
__global__ __launch_bounds__(256, 4) void gemm_qkv(
    const unsigned short* __restrict__ Ahi, const unsigned short* __restrict__ Alo,
    const unsigned short* __restrict__ Wth, const unsigned short* __restrict__ Wtl,
    const float* __restrict__ bq, const float* __restrict__ bk,
    const float* __restrict__ bv, const int* __restrict__ slotmap,
    unsigned short* __restrict__ qb, unsigned short* __restrict__ kc,
    unsigned short* __restrict__ vc)
{
    int z = blockIdx.z;
    int bx = blockIdx.x;
    int tid = threadIdx.x;
    int wave = tid >> 6, lane = tid & 63;
    int quad = lane >> 4, l16 = lane & 15;
    const unsigned short* Whi = Wth + (size_t)z * DIM * DIM;
    const unsigned short* Wlo = Wtl + (size_t)z * DIM * DIM;
    int mrow0, ncol0;
    const unsigned short *Phi, *Plo, *Shi, *Slo;
    if (z < 2) {
        mrow0 = (bx >> 3) * 128 + wave * 32;   // xn rows
        ncol0 = (bx & 7) * 32;                 // W^T cols
        Phi = Ahi; Plo = Alo; Shi = Whi; Slo = Wlo;
    } else {
        mrow0 = (bx / 288) * 128 + wave * 32;  // Wv^T rows (c-dim)
        ncol0 = (bx % 288) * 32;               // xn rows
        Phi = Whi; Plo = Wlo; Shi = Ahi; Slo = Alo;
    }
    f32x4 acc[2][2] = {};
    #pragma unroll
    for (int k0 = 0; k0 < DIM; k0 += 32) {
        size_t at = (((size_t)(mrow0 >> 4) * 8 + (k0 >> 5)) << 9) + lane * 8;
        size_t bt = (((size_t)(ncol0 >> 4) * 8 + (k0 >> 5)) << 9) + lane * 8;
        short8 ah0 = *(const short8*)&Phi[at];
        short8 al0 = *(const short8*)&Plo[at];
        short8 ah1 = *(const short8*)&Phi[at + 4096];
        short8 al1 = *(const short8*)&Plo[at + 4096];
        short8 bh0 = *(const short8*)&Shi[bt];
        short8 bl0 = *(const short8*)&Slo[bt];
        short8 bh1 = *(const short8*)&Shi[bt + 4096];
        short8 bl1 = *(const short8*)&Slo[bt + 4096];
        acc[0][0] = __builtin_amdgcn_mfma_f32_16x16x32_bf16(ah0, bh0, acc[0][0], 0, 0, 0);
        acc[0][0] = __builtin_amdgcn_mfma_f32_16x16x32_bf16(ah0, bl0, acc[0][0], 0, 0, 0);
        acc[0][0] = __builtin_amdgcn_mfma_f32_16x16x32_bf16(al0, bh0, acc[0][0], 0, 0, 0);
        acc[0][1] = __builtin_amdgcn_mfma_f32_16x16x32_bf16(ah0, bh1, acc[0][1], 0, 0, 0);
        acc[0][1] = __builtin_amdgcn_mfma_f32_16x16x32_bf16(ah0, bl1, acc[0][1], 0, 0, 0);
        acc[0][1] = __builtin_amdgcn_mfma_f32_16x16x32_bf16(al0, bh1, acc[0][1], 0, 0, 0);
        acc[1][0] = __builtin_amdgcn_mfma_f32_16x16x32_bf16(ah1, bh0, acc[1][0], 0, 0, 0);
        acc[1][0] = __builtin_amdgcn_mfma_f32_16x16x32_bf16(ah1, bl0, acc[1][0], 0, 0, 0);
        acc[1][0] = __builtin_amdgcn_mfma_f32_16x16x32_bf16(al1, bh0, acc[1][0], 0, 0, 0);
        acc[1][1] = __builtin_amdgcn_mfma_f32_16x16x32_bf16(ah1, bh1, acc[1][1], 0, 0, 0);
        acc[1][1] = __builtin_amdgcn_mfma_f32_16x16x32_bf16(ah1, bl1, acc[1][1], 0, 0, 0);
        acc[1][1] = __builtin_amdgcn_mfma_f32_16x16x32_bf16(al1, bh1, acc[1][1], 0, 0, 0);
    }
    if (z < 2) {
        const float* bias = z ? bk : bq;
        int b = mrow0 / N;
        int nbase = mrow0 - b * N;
        const int* smap = slotmap + (size_t)b * N;
        #pragma unroll
        for (int j = 0; j < 2; ++j) {
            int c = ncol0 + j * 16 + l16;
            int h = c >> 5, d = c & 31;
            float bs = bias[c];
            unsigned short* ob = z
                ? kc + (size_t)(b * NH + h) * CST
                : qb + (size_t)(b * NH + h) * ((size_t)N * DH);
            #pragma unroll
            for (int i = 0; i < 2; ++i)
            #pragma unroll
            for (int r = 0; r < 4; ++r) {
                int n = nbase + i * 16 + quad * 4 + r;
                int slot = z ? smap[n] : n;
                ob[foQK(slot, d)] = f2bf(acc[i][j][r] + bs);
            }
        }
    } else {
        int b = ncol0 / N;
        int kbase = ncol0 - b * N;
        const int* smap = slotmap + (size_t)b * N;
        #pragma unroll
        for (int i = 0; i < 2; ++i)
        #pragma unroll
        for (int r = 0; r < 4; ++r) {
            int m = mrow0 + i * 16 + quad * 4 + r;
            int h = m >> 5, d = m & 31;
            float bs = bv[m];
            unsigned short* ob = vc + (size_t)(b * NH + h) * CST;
            #pragma unroll
            for (int j = 0; j < 2; ++j) {
                int slot = smap[kbase + j * 16 + l16];
                ob[foVTC(d, slot)] = f2bf(acc[i][j][r] + bs);
            }
        }
    }
}

// ---------------- masked-V row sums: vm[bh][d] = sum over masked keys ------
__global__ __launch_bounds__(256) void vmsum_kernel(
    const unsigned short* __restrict__ vc, const int* __restrict__ ncp,
    float* __restrict__ vm)
{
    __shared__ float part[8][32];
    int bh = blockIdx.x, b = bh >> 3;
    int t = threadIdx.x;
    int d = t & 31, grp = t >> 5;
    int Nc = ncp[b * 2], Nkp = ncp[b * 2 + 1];
    int mend = Nkp + (N - Nc);
    const unsigned short* vcb = vc + (size_t)bh * CST;
    float s = 0.f;
    for (int i = Nkp + grp; i < mend; i += 8)
        s += bf2f(vcb[foVTC(d, i)]);
    part[grp][d] = s;
    __syncthreads();
    if (grp == 0) {
        float a = 0.f;
        #pragma unroll
        for (int g = 0; g < 8; ++g) a += part[g][d];
        vm[bh * 32 + d] = a;
    }
}

// ---------------- MFMA flash attention over COMPACT keys -------------------
// Only unmasked keys carry scores; pad slots [Nc,Nkp) get p=0 via select
// (exact). Masked-key contributions added analytically in combine.
__global__ __launch_bounds__(256, 4) void attn_kernel(
    const unsigned short* __restrict__ Qb,
    const unsigned short* __restrict__ Kc,
    const unsigned short* __restrict__ Vc,
    const int* __restrict__ ncp,
    float* __restrict__ po, float* __restrict__ pl)
{
    __shared__ unsigned short pbuf[8 * 16 * 40];   // (wave,tile) x 16 x 40
    int tid  = threadIdx.x;
    int wave = tid >> 6, lane = tid & 63;
    int quad = lane >> 4, l16 = lane & 15;
    int bh = blockIdx.y, b = bh >> 3;
    int sp = blockIdx.z;
    int q0 = (blockIdx.x * 4 + wave) * 32;

    const unsigned short* Qf = Qb + (size_t)bh * ((size_t)N * DH);
    const unsigned short* Kf = Kc + (size_t)bh * CST;
    const unsigned short* Vf = Vc + (size_t)bh * CST;

    int Nc  = ncp[b * 2];
    int Nkp = ncp[b * 2 + 1];
    int chunks = Nkp >> 5;
    int cbeg = sp ? (chunks >> 1) : 0;
    int cend = sp ? chunks : (chunks >> 1);
    int kbeg = cbeg << 5, kend = cend << 5;

    short8 qA0 = *(const short8*)&Qf[((size_t)(q0 >> 4) << 9) + lane * 8];
    short8 qA1 = *(const short8*)&Qf[((size_t)((q0 >> 4) + 1) << 9) + lane * 8];

    f32x4 o00 = {0,0,0,0}, o01 = {0,0,0,0}, o10 = {0,0,0,0}, o11 = {0,0,0,0};
    float l0[4] = {0,0,0,0}, l1[4] = {0,0,0,0};

    unsigned short* pb0 = &pbuf[(wave * 2 + 0) * 640];
    unsigned short* pb1 = &pbuf[(wave * 2 + 1) * 640];

    short8 kB0 = *(const short8*)&Kf[((size_t)(kbeg >> 4) << 9) + lane * 8];
    short8 kB1 = *(const short8*)&Kf[((size_t)((kbeg >> 4) + 1) << 9) + lane * 8];
    short8 vB0 = *(const short8*)&Vf[((size_t)(kbeg >> 5) << 9) + lane * 8];
    short8 vB1 = *(const short8*)&Vf[((size_t)((SLOTS / 32) + (kbeg >> 5)) << 9) + lane * 8];

    for (int k0 = kbeg; k0 < kend; k0 += 32) {
        int kn = (k0 + 32 < kend) ? k0 + 32 : kbeg;   // branchless wrap prefetch
        short8 nk0 = *(const short8*)&Kf[((size_t)(kn >> 4) << 9) + lane * 8];
        short8 nk1 = *(const short8*)&Kf[((size_t)((kn >> 4) + 1) << 9) + lane * 8];
        short8 nv0 = *(const short8*)&Vf[((size_t)(kn >> 5) << 9) + lane * 8];
        short8 nv1 = *(const short8*)&Vf[((size_t)((SLOTS / 32) + (kn >> 5)) << 9) + lane * 8];

        bool in0 = (k0 + l16) < Nc;          // pad slots -> p = 0 (exact)
        bool in1 = (k0 + 16 + l16) < Nc;
        f32x4 z = {0,0,0,0};
        f32x4 s00 = __builtin_amdgcn_mfma_f32_16x16x32_bf16(qA0, kB0, z, 0, 0, 0);
        f32x4 s01 = __builtin_amdgcn_mfma_f32_16x16x32_bf16(qA0, kB1, z, 0, 0, 0);
        f32x4 s10 = __builtin_amdgcn_mfma_f32_16x16x32_bf16(qA1, kB0, z, 0, 0, 0);
        f32x4 s11 = __builtin_amdgcn_mfma_f32_16x16x32_bf16(qA1, kB1, z, 0, 0, 0);
        #pragma unroll
        for (int r = 0; r < 4; ++r) {
            int row = quad * 4 + r;
            float p00 = in0 ? __expf(s00[r]) : 0.f;
            float p01 = in1 ? __expf(s01[r]) : 0.f;
            float p10 = in0 ? __expf(s10[r]) : 0.f;
            float p11 = in1 ? __expf(s11[r]) : 0.f;
            l0[r] += p00 + p01;
            l1[r] += p10 + p11;
            pb0[row * 40 + l16]      = f2bf_trunc(p00);
            pb0[row * 40 + 16 + l16] = f2bf_trunc(p01);
            pb1[row * 40 + l16]      = f2bf_trunc(p10);
            pb1[row * 40 + 16 + l16] = f2bf_trunc(p11);
        }
        short8 pA0 = *(const short8*)&pb0[l16 * 40 + quad * 8];
        short8 pA1 = *(const short8*)&pb1[l16 * 40 + quad * 8];
        o00 = __builtin_amdgcn_mfma_f32_16x16x32_bf16(pA0, vB0, o00, 0, 0, 0);
        o01 = __builtin_amdgcn_mfma_f32_16x16x32_bf16(pA0, vB1, o01, 0, 0, 0);
        o10 = __builtin_amdgcn_mfma_f32_16x16x32_bf16(pA1, vB0, o10, 0, 0, 0);
        o11 = __builtin_amdgcn_mfma_f32_16x16x32_bf16(pA1, vB1, o11, 0, 0, 0);

        kB0 = nk0; kB1 = nk1; vB0 = nv0; vB1 = nv1;
    }
    #pragma unroll
    for (int r = 0; r < 4; ++r) {
        #pragma unroll
        for (int off = 1; off < 16; off <<= 1) {
            l0[r] += __shfl_xor(l0[r], off, 64);
            l1[r] += __shfl_xor(l1[r], off, 64);
        }
    }
    size_t pbase = (size_t)(bh * 2 + sp) * N;
    #pragma unroll
    for (int r = 0; r < 4; ++r) {
        int row = quad * 4 + r;
        size_t b0 = (pbase + q0 + row) * DH;
        size_t b1 = (pbase + q0 + 16 + row) * DH;
        po[b0 + l16]      = o00[r];
        po[b0 + 16 + l16] = o01[r];
        po[b1 + l16]      = o10[r];
        po[b1 + 16 + l16] = o11[r];
        if (l16 == 0) {
            pl[pbase + q0 + row]      = l0[r];
            pl[pbase + q0 + 16 + row] = l1[r];
        }
    }
}

// ------- combine key-split partials + analytic masked part -> FragTile -----
__global__ __launch_bounds__(256) void combine_kernel(
    const float* __restrict__ po, const float* __restrict__ pl,
    const float* __restrict__ vm, const int* __restrict__ ncp,
    unsigned short* __restrict__ ahn_hi, unsigned short* __restrict__ ahn_lo)
{
    int idx = blockIdx.x * 256 + threadIdx.x;   // [0, B*NH*N*4)
    int bhq = idx >> 2;
    int dg  = (idx & 3) * 8;
    int bh = bhq / N, q = bhq - bh * N;
    int b = bh >> 3, h = bh & 7;
    size_t p0 = ((size_t)(bh * 2 + 0) * N + q) * DH + dg;
    size_t p1 = ((size_t)(bh * 2 + 1) * N + q) * DH + dg;
    int Nc = ncp[b * 2];
    float l = pl[(size_t)(bh * 2) * N + q] + pl[(size_t)(bh * 2 + 1) * N + q]
            + (float)(N - Nc);                  // masked cols: exp(0)=1 each
    float inv = 1.f / l;
    float4 a0 = *(const float4*)&po[p0];
    float4 a1 = *(const float4*)&po[p0 + 4];
    float4 c0 = *(const float4*)&po[p1];
    float4 c1 = *(const float4*)&po[p1 + 4];
    float4 m0 = *(const float4*)&vm[bh * 32 + dg];
    float4 m1 = *(const float4*)&vm[bh * 32 + dg + 4];
    float vals[8] = {
        (a0.x + c0.x + m0.x) * inv, (a0.y + c0.y + m0.y) * inv,
        (a0.z + c0.z + m0.z) * inv, (a0.w + c0.w + m0.w) * inv,
        (a1.x + c1.x + m1.x) * inv, (a1.y + c1.y + m1.y) * inv,
        (a1.z + c1.z + m1.z) * inv, (a1.w + c1.w + m1.w) * inv };
    union { unsigned short u[8]; short8 v; } hi, lo;
    #pragma unroll
    for (int j = 0; j < 8; ++j) {
        unsigned short t = f2bf(vals[j]);
        hi.u[j] = t;
        lo.u[j] = f2bf(vals[j] - bf2f(t));
    }
    size_t o = fo256(b * N + q, h * 32 + dg);
    *(short8*)&ahn_hi[o] = hi.v;
    *(short8*)&ahn_lo[o] = lo.v;
}

// ---------------- final projection GEMM: fp32 row-major out ----------------
__global__ __launch_bounds__(256, 4) void gemm_p(
    const unsigned short* __restrict__ Ahi, const unsigned short* __restrict__ Alo,
    const unsigned short* __restrict__ Wth, const unsigned short* __restrict__ Wtl,
    const float* __restrict__ bias, float* __restrict__ out)
{
    const unsigned short* Bhi = Wth + (size_t)3 * DIM * DIM;
    const unsigned short* Blo = Wtl + (size_t)3 * DIM * DIM;
    int tid = threadIdx.x;
    int wave = tid >> 6, lane = tid & 63;
    int quad = lane >> 4, l16 = lane & 15;
    int r0 = blockIdx.y * 128 + wave * 32;
    int c0 = blockIdx.x * 16;
    f32x4 acc0 = {}, acc1 = {};
    #pragma unroll
    for (int k0 = 0; k0 < DIM; k0 += 32) {
        size_t at = (((size_t)(r0 >> 4) * 8 + (k0 >> 5)) << 9) + lane * 8;
        size_t bt = (((size_t)(c0 >> 4) * 8 + (k0 >> 5)) << 9) + lane * 8;
        short8 ah0 = *(const short8*)&Ahi[at];
        short8 al0 = *(const short8*)&Alo[at];
        short8 ah1 = *(const short8*)&Ahi[at + 4096];
        short8 al1 = *(const short8*)&Alo[at + 4096];
        short8 bh = *(const short8*)&Bhi[bt];
        short8 bl = *(const short8*)&Blo[bt];
        acc0 = __builtin_amdgcn_mfma_f32_16x16x32_bf16(ah0, bh, acc0, 0, 0, 0);
        acc0 = __builtin_amdgcn_mfma_f32_16x16x32_bf16(ah0, bl, acc0, 0, 0, 0);
        acc0 = __builtin_amdgcn_mfma_f32_16x16x32_bf16(al0, bh, acc0, 0, 0, 0);
        acc1 = __builtin_amdgcn_mfma_f32_16x16x32_bf16(ah1, bh, acc1, 0, 0, 0);
        acc1 = __builtin_amdgcn_mfma_f32_16x16x32_bf16(ah1, bl, acc1, 0, 0, 0);
        acc1 = __builtin_amdgcn_mfma_f32_16x16x32_bf16(al1, bh, acc1, 0, 0, 0);
    }
    int c = c0 + l16;
    float bs = bias[c];
    #pragma unroll
    for (int r = 0; r < 4; ++r) {
        int R0 = r0 + quad * 4 + r;
        out[(size_t)R0 * DIM + c] = acc0[r] + bs;
        out[(size_t)(R0 + 16) * DIM + c] = acc1[r] + bs;
    }
}

extern "C" void kernel_launch(void* const* d_in, const int* in_sizes, int n_in,
                              void* d_out, int out_size, void* d_ws, size_t ws_size,
                              hipStream_t stream)
{
    const float* x    = (const float*)d_in[0];
    const float* mask = (const float*)d_in[1];
    const float* ln_g = (const float*)d_in[2];
    const float* ln_b = (const float*)d_in[3];
    const float* Wq   = (const float*)d_in[4];
    const float* bq   = (const float*)d_in[5];
    const float* Wk   = (const float*)d_in[6];
    const float* bk   = (const float*)d_in[7];
    const float* Wv   = (const float*)d_in[8];
    const float* bv   = (const float*)d_in[9];
    const float* Wp   = (const float*)d_in[10];
    const float* bp   = (const float*)d_in[11];
    float* out = (float*)d_out;

    constexpr size_t SZ  = (size_t)M * DIM;          // 2359296
    constexpr size_t CSZ = (size_t)B * NH * CST;     // 2392064
    constexpr size_t WSZ = (size_t)DIM * DIM;        // 65536
    unsigned short* p = (unsigned short*)d_ws;
    unsigned short* xh = p;  p += SZ;
    unsigned short* xl = p;  p += SZ;
    unsigned short* qb = p;  p += SZ;
    unsigned short* kc = p;  p += CSZ;
    unsigned short* vc = p;  p += CSZ;
    unsigned short* ah = p;  p += SZ;   // attn out hi
    unsigned short* al = p;  p += SZ;   // attn out lo
    unsigned short* wth = p; p += 4 * WSZ;
    unsigned short* wtl = p; p += 4 * WSZ;
    float* po = (float*)p;                       // B*NH*2*N*DH fp32
    float* pl = po + (size_t)B * NH * 2 * N * DH;
    float* vm = pl + (size_t)B * NH * 2 * N;     // B*NH*32
    int* slotmap = (int*)(vm + (size_t)B * NH * 32);
    int* ncp = slotmap + (size_t)B * N;

    mask_scan<<<B, 256, 0, stream>>>(mask, slotmap, ncp);

    ln_kernel<<<M, 256, 0, stream>>>(x, ln_g, ln_b, xh, xl);

    split_w<<<dim3(8, 8, 4), 256, 0, stream>>>(Wq, Wk, Wv, Wp, wth, wtl);

    gemm_qkv<<<dim3(576, 1, 3), 256, 0, stream>>>(
        xh, xl, wth, wtl, bq, bk, bv, slotmap, qb, kc, vc);

    vmsum_kernel<<<B * NH, 256, 0, stream>>>(vc, ncp, vm);

    attn_kernel<<<dim3(N / 128, B * NH, 2), 256, 0, stream>>>(
        qb, kc, vc, ncp, po, pl);

    combine_kernel<<<(B * NH * N * 4) / 256, 256, 0, stream>>>(
        po, pl, vm, ncp, ah, al);

    gemm_p<<<dim3(DIM / 16, M / 128), 256, 0, stream>>>(
        ah, al, wth, wtl, bp, out);
}

// Round 8
// 175.169 us; speedup vs baseline: 1.2742x; 1.2742x over previous
//
#include <hip/hip_runtime.h>
#include <math.h>

typedef __attribute__((ext_vector_type(8))) short short8;
typedef __attribute__((ext_vector_type(4))) float f32x4;

constexpr int B   = 4;
constexpr int N   = 2304;
constexpr int DIM = 256;
constexpr int NH  = 8;
constexpr int DH  = 32;
constexpr int M   = B * N;          // 9216 rows
constexpr int SLOTS = 2336;         // N + 32: kept keys + pad + masked keys
constexpr int CST = SLOTS * DH;     // per-(b,h) compact K/V element count

// float -> bf16 round-to-nearest-even, truncation, and back
__device__ inline unsigned short f2bf(float f) {
    union { float f; unsigned u; } c; c.f = f;
    unsigned u = c.u;
    u += 0x7fffu + ((u >> 16) & 1u);
    return (unsigned short)(u >> 16);
}
__device__ inline unsigned short f2bf_trunc(float f) {
    union { float f; unsigned u; } c; c.f = f;
    return (unsigned short)(c.u >> 16);
}
__device__ inline float bf2f(unsigned short h) {
    union { unsigned u; float f; } c; c.u = ((unsigned)h) << 16;
    return c.f;
}

// ---- FragTile layouts: element (row r, contraction k) stored so an MFMA
// A/B-frag load (16 rows x 32 k) is ONE contiguous 1KB wave transaction.
__device__ inline size_t fo256(int r, int k) {   // [R x 256] tensors
    return ((size_t)((r >> 4) * 8 + (k >> 5)) << 9)
         + (size_t)(((((k & 31) >> 3) << 4) + (r & 15)) * 8 + (k & 7));
}
__device__ inline size_t foQK(int n, int d) {    // per-(b,h) [rows x 32]
    return ((size_t)(n >> 4) << 9)
         + (size_t)((((d >> 3) << 4) + (n & 15)) * 8 + (d & 7));
}
__device__ inline size_t foVTC(int d, int key) { // per-(b,h) [32 x SLOTS]
    return ((size_t)((d >> 4) * (SLOTS / 32) + (key >> 5)) << 9)
         + (size_t)(((((key & 31) >> 3) << 4) + (d & 15)) * 8 + (key & 7));
}

// ---------------- mask scan: kept/masked slot permutation per batch --------
// slot[n] = kept ? rank_kept(n) : Nkp + rank_masked(n).  Nkp = ceil32(Nc).
__global__ __launch_bounds__(256) void mask_scan(
    const float* __restrict__ mask, int* __restrict__ slotmap,
    int* __restrict__ ncp)
{
    __shared__ int wsum[4];
    int b = blockIdx.x, t = threadIdx.x;
    int wave = t >> 6, lane = t & 63;
    // pass 1: count kept
    int cnt = 0;
    for (int j = t; j < N; j += 256) cnt += (mask[(size_t)b * N + j] > 0.f);
    #pragma unroll
    for (int o = 32; o > 0; o >>= 1) cnt += __shfl_down(cnt, o, 64);
    if (lane == 0) wsum[wave] = cnt;
    __syncthreads();
    int Nc = wsum[0] + wsum[1] + wsum[2] + wsum[3];
    int Nkp = (Nc + 31) & ~31;
    if (t == 0) { ncp[b * 2] = Nc; ncp[b * 2 + 1] = Nkp; }
    // pass 2: ordered scan -> slots
    int baseK = 0;
    for (int j0 = 0; j0 < N; j0 += 256) {
        int j = j0 + t;
        bool keep = mask[(size_t)b * N + j] > 0.f;
        unsigned long long bal = __ballot(keep);
        int pos = __popcll(bal & ((1ull << lane) - 1ull));
        int wc  = __popcll(bal);
        __syncthreads();
        if (lane == 0) wsum[wave] = wc;
        __syncthreads();
        int wb = 0;
        for (int w = 0; w < wave; ++w) wb += wsum[w];
        int tot = wsum[0] + wsum[1] + wsum[2] + wsum[3];
        int keptBefore = baseK + wb + pos;
        slotmap[(size_t)b * N + j] = keep ? keptBefore : Nkp + (j - keptBefore);
        baseK += tot;
    }
}

// ---------- LayerNorm, barrier-free: ONE WAVE per row, 4 rows/block --------
__global__ __launch_bounds__(256) void ln_kernel(
    const float* __restrict__ x, const float* __restrict__ g,
    const float* __restrict__ bta,
    unsigned short* __restrict__ xh, unsigned short* __restrict__ xl)
{
    int tid = threadIdx.x;
    int wave = tid >> 6, lane = tid & 63;
    int row = blockIdx.x * 4 + wave;
    float4 v = *(const float4*)&x[(size_t)row * DIM + lane * 4];
    float s = v.x + v.y + v.z + v.w;
    #pragma unroll
    for (int o = 32; o > 0; o >>= 1) s += __shfl_xor(s, o, 64);
    float mu = s * (1.0f / DIM);
    float d0 = v.x - mu, d1 = v.y - mu, d2 = v.z - mu, d3 = v.w - mu;
    float s2 = d0 * d0 + d1 * d1 + d2 * d2 + d3 * d3;
    #pragma unroll
    for (int o = 32; o > 0; o >>= 1) s2 += __shfl_xor(s2, o, 64);
    float r = rsqrtf(s2 * (1.0f / DIM) + 1e-5f);
    float4 gg = *(const float4*)&g[lane * 4];
    float4 bb = *(const float4*)&bta[lane * 4];
    float y0 = d0 * r * gg.x + bb.x;
    float y1 = d1 * r * gg.y + bb.y;
    float y2 = d2 * r * gg.z + bb.z;
    float y3 = d3 * r * gg.w + bb.w;
    ushort4 hi, lo;
    hi.x = f2bf(y0); lo.x = f2bf(y0 - bf2f(hi.x));
    hi.y = f2bf(y1); lo.y = f2bf(y1 - bf2f(hi.y));
    hi.z = f2bf(y2); lo.z = f2bf(y2 - bf2f(hi.z));
    hi.w = f2bf(y3); lo.w = f2bf(y3 - bf2f(hi.w));
    size_t o = fo256(row, lane * 4);   // 4 consecutive elems, one 8B store
    *(ushort4*)&xh[o] = hi;
    *(ushort4*)&xl[o] = lo;
}

// ---------------- all 4 W (256x256 fp32) -> W^T hi/lo FragTile -------------
__global__ __launch_bounds__(256) void split_w(
    const float* __restrict__ Wq, const float* __restrict__ Wk,
    const float* __restrict__ Wv, const float* __restrict__ Wp,
    unsigned short* __restrict__ Wth, unsigned short* __restrict__ Wtl)
{
    int z = blockIdx.z;
    const float* W = (z == 0) ? Wq : (z == 1) ? Wk : (z == 2) ? Wv : Wp;
    unsigned short* oh = Wth + (size_t)z * DIM * DIM;
    unsigned short* ol = Wtl + (size_t)z * DIM * DIM;
    __shared__ float t[32][33];
    int tid = threadIdx.x;
    int tx = tid & 31, ty0 = tid >> 5;
    int n0 = blockIdx.x * 32, k0 = blockIdx.y * 32;
    for (int ty = ty0; ty < 32; ty += 8)
        t[ty][tx] = W[(size_t)(k0 + ty) * DIM + n0 + tx];
    __syncthreads();
    for (int nn = ty0; nn < 32; nn += 8) {
        float v = t[tx][nn];                 // = W[k0+tx][n0+nn] = Wt[n][k]
        unsigned short hh = f2bf(v);
        size_t o = fo256(n0 + nn, k0 + tx);
        oh[o] = hh;
        ol[o] = f2bf(v - bf2f(hh));
    }
}

// ---------------- fused Q/K/V split-bf16 MFMA GEMM -------------------------
// z=0: Q (full), z=1: K -> compact slots, z=2: V^T -> compact slots.
__global__ __launch_bounds__(256, 4) void gemm_qkv(
    const unsigned short* __restrict__ Ahi, const unsigned short* __restrict__ Alo,
    const unsigned short* __restrict__ Wth, const unsigned short* __restrict__ Wtl,
    const float* __restrict__ bq, const float* __restrict__ bk,
    const float* __restrict__ bv, const int* __restrict__ slotmap,
    unsigned short* __restrict__ qb, unsigned short* __restrict__ kc,
    unsigned short* __restrict__ vc)
{
    int z = blockIdx.z;
    int bx = blockIdx.x;
    int tid = threadIdx.x;
    int wave = tid >> 6, lane = tid & 63;
    int quad = lane >> 4, l16 = lane & 15;
    const unsigned short* Whi = Wth + (size_t)z * DIM * DIM;
    const unsigned short* Wlo = Wtl + (size_t)z * DIM * DIM;
    int mrow0, ncol0;
    const unsigned short *Phi, *Plo, *Shi, *Slo;
    if (z < 2) {
        mrow0 = (bx >> 3) * 128 + wave * 32;   // xn rows
        ncol0 = (bx & 7) * 32;                 // W^T cols
        Phi = Ahi; Plo = Alo; Shi = Whi; Slo = Wlo;
    } else {
        mrow0 = (bx / 288) * 128 + wave * 32;  // Wv^T rows (c-dim)
        ncol0 = (bx % 288) * 32;               // xn rows
        Phi = Whi; Plo = Wlo; Shi = Ahi; Slo = Alo;
    }
    f32x4 acc[2][2] = {};
    #pragma unroll
    for (int k0 = 0; k0 < DIM; k0 += 32) {
        size_t at = (((size_t)(mrow0 >> 4) * 8 + (k0 >> 5)) << 9) + lane * 8;
        size_t bt = (((size_t)(ncol0 >> 4) * 8 + (k0 >> 5)) << 9) + lane * 8;
        short8 ah0 = *(const short8*)&Phi[at];
        short8 al0 = *(const short8*)&Plo[at];
        short8 ah1 = *(const short8*)&Phi[at + 4096];
        short8 al1 = *(const short8*)&Plo[at + 4096];
        short8 bh0 = *(const short8*)&Shi[bt];
        short8 bl0 = *(const short8*)&Slo[bt];
        short8 bh1 = *(const short8*)&Shi[bt + 4096];
        short8 bl1 = *(const short8*)&Slo[bt + 4096];
        acc[0][0] = __builtin_amdgcn_mfma_f32_16x16x32_bf16(ah0, bh0, acc[0][0], 0, 0, 0);
        acc[0][0] = __builtin_amdgcn_mfma_f32_16x16x32_bf16(ah0, bl0, acc[0][0], 0, 0, 0);
        acc[0][0] = __builtin_amdgcn_mfma_f32_16x16x32_bf16(al0, bh0, acc[0][0], 0, 0, 0);
        acc[0][1] = __builtin_amdgcn_mfma_f32_16x16x32_bf16(ah0, bh1, acc[0][1], 0, 0, 0);
        acc[0][1] = __builtin_amdgcn_mfma_f32_16x16x32_bf16(ah0, bl1, acc[0][1], 0, 0, 0);
        acc[0][1] = __builtin_amdgcn_mfma_f32_16x16x32_bf16(al0, bh1, acc[0][1], 0, 0, 0);
        acc[1][0] = __builtin_amdgcn_mfma_f32_16x16x32_bf16(ah1, bh0, acc[1][0], 0, 0, 0);
        acc[1][0] = __builtin_amdgcn_mfma_f32_16x16x32_bf16(ah1, bl0, acc[1][0], 0, 0, 0);
        acc[1][0] = __builtin_amdgcn_mfma_f32_16x16x32_bf16(al1, bh0, acc[1][0], 0, 0, 0);
        acc[1][1] = __builtin_amdgcn_mfma_f32_16x16x32_bf16(ah1, bh1, acc[1][1], 0, 0, 0);
        acc[1][1] = __builtin_amdgcn_mfma_f32_16x16x32_bf16(ah1, bl1, acc[1][1], 0, 0, 0);
        acc[1][1] = __builtin_amdgcn_mfma_f32_16x16x32_bf16(al1, bh1, acc[1][1], 0, 0, 0);
    }
    if (z < 2) {
        const float* bias = z ? bk : bq;
        int b = mrow0 / N;
        int nbase = mrow0 - b * N;
        const int* smap = slotmap + (size_t)b * N;
        #pragma unroll
        for (int j = 0; j < 2; ++j) {
            int c = ncol0 + j * 16 + l16;
            int h = c >> 5, d = c & 31;
            float bs = bias[c];
            unsigned short* ob = z
                ? kc + (size_t)(b * NH + h) * CST
                : qb + (size_t)(b * NH + h) * ((size_t)N * DH);
            #pragma unroll
            for (int i = 0; i < 2; ++i)
            #pragma unroll
            for (int r = 0; r < 4; ++r) {
                int n = nbase + i * 16 + quad * 4 + r;
                int slot = z ? smap[n] : n;
                ob[foQK(slot, d)] = f2bf(acc[i][j][r] + bs);
            }
        }
    } else {
        int b = ncol0 / N;
        int kbase = ncol0 - b * N;
        const int* smap = slotmap + (size_t)b * N;
        #pragma unroll
        for (int i = 0; i < 2; ++i)
        #pragma unroll
        for (int r = 0; r < 4; ++r) {
            int m = mrow0 + i * 16 + quad * 4 + r;
            int h = m >> 5, d = m & 31;
            float bs = bv[m];
            unsigned short* ob = vc + (size_t)(b * NH + h) * CST;
            #pragma unroll
            for (int j = 0; j < 2; ++j) {
                int slot = smap[kbase + j * 16 + l16];
                ob[foVTC(d, slot)] = f2bf(acc[i][j][r] + bs);
            }
        }
    }
}

// -------- masked-V row sums, parallel: vm[bh][d] += tiles (atomic) ---------
// Wave eats whole 1KB FragTile tiles: lane = kq*16 + d15 -> one short8 load;
// per-element bound mask vs mend; quad-reduce via shfl_xor(16,32); 16
// atomicAdds per tile. vm must be zeroed (hipMemsetAsync) before launch.
__global__ __launch_bounds__(256) void vmsum_kernel(
    const unsigned short* __restrict__ vc, const int* __restrict__ ncp,
    float* __restrict__ vm)
{
    int bh = blockIdx.x, b = bh >> 3;
    int tid = threadIdx.x;
    int wave = tid >> 6, lane = tid & 63;
    int kq = lane >> 4, l16 = lane & 15;
    int Nc = ncp[b * 2], Nkp = ncp[b * 2 + 1];
    int mend = Nkp + (N - Nc);
    int tbeg = Nkp >> 5, tend = (mend + 31) >> 5;
    int wgid = blockIdx.y * 4 + wave;          // global wave id within bh
    const int WSTEP = 32;                      // gridDim.y * 4
    const unsigned short* vcb = vc + (size_t)bh * CST;
    #pragma unroll
    for (int dt = 0; dt < 2; ++dt) {
        float s = 0.f;
        for (int t = tbeg + wgid; t < tend; t += WSTEP) {
            short8 v = *(const short8*)&vcb[((size_t)(dt * (SLOTS / 32) + t) << 9) + lane * 8];
            int keyb = t * 32 + kq * 8;
            #pragma unroll
            for (int j = 0; j < 8; ++j)
                s += (keyb + j < mend) ? bf2f((unsigned short)v[j]) : 0.f;
        }
        s += __shfl_xor(s, 16, 64);
        s += __shfl_xor(s, 32, 64);
        if (lane < 16) atomicAdd(&vm[bh * 32 + dt * 16 + l16], s);
    }
}

// ---------------- MFMA flash attention over COMPACT keys -------------------
// Only unmasked keys carry scores; pad slots [Nc,Nkp) get p=0 via select
// (exact). Masked-key contributions added analytically in combine.
__global__ __launch_bounds__(256, 4) void attn_kernel(
    const unsigned short* __restrict__ Qb,
    const unsigned short* __restrict__ Kc,
    const unsigned short* __restrict__ Vc,
    const int* __restrict__ ncp,
    float* __restrict__ po, float* __restrict__ pl)
{
    __shared__ unsigned short pbuf[8 * 16 * 40];   // (wave,tile) x 16 x 40
    int tid  = threadIdx.x;
    int wave = tid >> 6, lane = tid & 63;
    int quad = lane >> 4, l16 = lane & 15;
    int bh = blockIdx.y, b = bh >> 3;
    int sp = blockIdx.z;
    int q0 = (blockIdx.x * 4 + wave) * 32;

    const unsigned short* Qf = Qb + (size_t)bh * ((size_t)N * DH);
    const unsigned short* Kf = Kc + (size_t)bh * CST;
    const unsigned short* Vf = Vc + (size_t)bh * CST;

    int Nc  = ncp[b * 2];
    int Nkp = ncp[b * 2 + 1];
    int chunks = Nkp >> 5;
    int cbeg = sp ? (chunks >> 1) : 0;
    int cend = sp ? chunks : (chunks >> 1);
    int kbeg = cbeg << 5, kend = cend << 5;

    short8 qA0 = *(const short8*)&Qf[((size_t)(q0 >> 4) << 9) + lane * 8];
    short8 qA1 = *(const short8*)&Qf[((size_t)((q0 >> 4) + 1) << 9) + lane * 8];

    f32x4 o00 = {0,0,0,0}, o01 = {0,0,0,0}, o10 = {0,0,0,0}, o11 = {0,0,0,0};
    float l0[4] = {0,0,0,0}, l1[4] = {0,0,0,0};

    unsigned short* pb0 = &pbuf[(wave * 2 + 0) * 640];
    unsigned short* pb1 = &pbuf[(wave * 2 + 1) * 640];

    short8 kB0 = *(const short8*)&Kf[((size_t)(kbeg >> 4) << 9) + lane * 8];
    short8 kB1 = *(const short8*)&Kf[((size_t)((kbeg >> 4) + 1) << 9) + lane * 8];
    short8 vB0 = *(const short8*)&Vf[((size_t)(kbeg >> 5) << 9) + lane * 8];
    short8 vB1 = *(const short8*)&Vf[((size_t)((SLOTS / 32) + (kbeg >> 5)) << 9) + lane * 8];

    for (int k0 = kbeg; k0 < kend; k0 += 32) {
        int kn = (k0 + 32 < kend) ? k0 + 32 : kbeg;   // branchless wrap prefetch
        short8 nk0 = *(const short8*)&Kf[((size_t)(kn >> 4) << 9) + lane * 8];
        short8 nk1 = *(const short8*)&Kf[((size_t)((kn >> 4) + 1) << 9) + lane * 8];
        short8 nv0 = *(const short8*)&Vf[((size_t)(kn >> 5) << 9) + lane * 8];
        short8 nv1 = *(const short8*)&Vf[((size_t)((SLOTS / 32) + (kn >> 5)) << 9) + lane * 8];

        bool in0 = (k0 + l16) < Nc;          // pad slots -> p = 0 (exact)
        bool in1 = (k0 + 16 + l16) < Nc;
        f32x4 z = {0,0,0,0};
        f32x4 s00 = __builtin_amdgcn_mfma_f32_16x16x32_bf16(qA0, kB0, z, 0, 0, 0);
        f32x4 s01 = __builtin_amdgcn_mfma_f32_16x16x32_bf16(qA0, kB1, z, 0, 0, 0);
        f32x4 s10 = __builtin_amdgcn_mfma_f32_16x16x32_bf16(qA1, kB0, z, 0, 0, 0);
        f32x4 s11 = __builtin_amdgcn_mfma_f32_16x16x32_bf16(qA1, kB1, z, 0, 0, 0);
        #pragma unroll
        for (int r = 0; r < 4; ++r) {
            int row = quad * 4 + r;
            float p00 = in0 ? __expf(s00[r]) : 0.f;
            float p01 = in1 ? __expf(s01[r]) : 0.f;
            float p10 = in0 ? __expf(s10[r]) : 0.f;
            float p11 = in1 ? __expf(s11[r]) : 0.f;
            l0[r] += p00 + p01;
            l1[r] += p10 + p11;
            pb0[row * 40 + l16]      = f2bf_trunc(p00);
            pb0[row * 40 + 16 + l16] = f2bf_trunc(p01);
            pb1[row * 40 + l16]      = f2bf_trunc(p10);
            pb1[row * 40 + 16 + l16] = f2bf_trunc(p11);
        }
        short8 pA0 = *(const short8*)&pb0[l16 * 40 + quad * 8];
        short8 pA1 = *(const short8*)&pb1[l16 * 40 + quad * 8];
        o00 = __builtin_amdgcn_mfma_f32_16x16x32_bf16(pA0, vB0, o00, 0, 0, 0);
        o01 = __builtin_amdgcn_mfma_f32_16x16x32_bf16(pA0, vB1, o01, 0, 0, 0);
        o10 = __builtin_amdgcn_mfma_f32_16x16x32_bf16(pA1, vB0, o10, 0, 0, 0);
        o11 = __builtin_amdgcn_mfma_f32_16x16x32_bf16(pA1, vB1, o11, 0, 0, 0);

        kB0 = nk0; kB1 = nk1; vB0 = nv0; vB1 = nv1;
    }
    #pragma unroll
    for (int r = 0; r < 4; ++r) {
        #pragma unroll
        for (int off = 1; off < 16; off <<= 1) {
            l0[r] += __shfl_xor(l0[r], off, 64);
            l1[r] += __shfl_xor(l1[r], off, 64);
        }
    }
    size_t pbase = (size_t)(bh * 2 + sp) * N;
    #pragma unroll
    for (int r = 0; r < 4; ++r) {
        int row = quad * 4 + r;
        size_t b0 = (pbase + q0 + row) * DH;
        size_t b1 = (pbase + q0 + 16 + row) * DH;
        po[b0 + l16]      = o00[r];
        po[b0 + 16 + l16] = o01[r];
        po[b1 + l16]      = o10[r];
        po[b1 + 16 + l16] = o11[r];
        if (l16 == 0) {
            pl[pbase + q0 + row]      = l0[r];
            pl[pbase + q0 + 16 + row] = l1[r];
        }
    }
}

// ------- combine key-split partials + analytic masked part -> FragTile -----
__global__ __launch_bounds__(256) void combine_kernel(
    const float* __restrict__ po, const float* __restrict__ pl,
    const float* __restrict__ vm, const int* __restrict__ ncp,
    unsigned short* __restrict__ ahn_hi, unsigned short* __restrict__ ahn_lo)
{
    int idx = blockIdx.x * 256 + threadIdx.x;   // [0, B*NH*N*4)
    int bhq = idx >> 2;
    int dg  = (idx & 3) * 8;
    int bh = bhq / N, q = bhq - bh * N;
    int b = bh >> 3, h = bh & 7;
    size_t p0 = ((size_t)(bh * 2 + 0) * N + q) * DH + dg;
    size_t p1 = ((size_t)(bh * 2 + 1) * N + q) * DH + dg;
    int Nc = ncp[b * 2];
    float l = pl[(size_t)(bh * 2) * N + q] + pl[(size_t)(bh * 2 + 1) * N + q]
            + (float)(N - Nc);                  // masked cols: exp(0)=1 each
    float inv = 1.f / l;
    float4 a0 = *(const float4*)&po[p0];
    float4 a1 = *(const float4*)&po[p0 + 4];
    float4 c0 = *(const float4*)&po[p1];
    float4 c1 = *(const float4*)&po[p1 + 4];
    float4 m0 = *(const float4*)&vm[bh * 32 + dg];
    float4 m1 = *(const float4*)&vm[bh * 32 + dg + 4];
    float vals[8] = {
        (a0.x + c0.x + m0.x) * inv, (a0.y + c0.y + m0.y) * inv,
        (a0.z + c0.z + m0.z) * inv, (a0.w + c0.w + m0.w) * inv,
        (a1.x + c1.x + m1.x) * inv, (a1.y + c1.y + m1.y) * inv,
        (a1.z + c1.z + m1.z) * inv, (a1.w + c1.w + m1.w) * inv };
    union { unsigned short u[8]; short8 v; } hi, lo;
    #pragma unroll
    for (int j = 0; j < 8; ++j) {
        unsigned short t = f2bf(vals[j]);
        hi.u[j] = t;
        lo.u[j] = f2bf(vals[j] - bf2f(t));
    }
    size_t o = fo256(b * N + q, h * 32 + dg);
    *(short8*)&ahn_hi[o] = hi.v;
    *(short8*)&ahn_lo[o] = lo.v;
}

// ---------------- final projection GEMM: fp32 row-major out ----------------
__global__ __launch_bounds__(256, 4) void gemm_p(
    const unsigned short* __restrict__ Ahi, const unsigned short* __restrict__ Alo,
    const unsigned short* __restrict__ Wth, const unsigned short* __restrict__ Wtl,
    const float* __restrict__ bias, float* __restrict__ out)
{
    const unsigned short* Bhi = Wth + (size_t)3 * DIM * DIM;
    const unsigned short* Blo = Wtl + (size_t)3 * DIM * DIM;
    int tid = threadIdx.x;
    int wave = tid >> 6, lane = tid & 63;
    int quad = lane >> 4, l16 = lane & 15;
    int r0 = blockIdx.y * 128 + wave * 32;
    int c0 = blockIdx.x * 16;
    f32x4 acc0 = {}, acc1 = {};
    #pragma unroll
    for (int k0 = 0; k0 < DIM; k0 += 32) {
        size_t at = (((size_t)(r0 >> 4) * 8 + (k0 >> 5)) << 9) + lane * 8;
        size_t bt = (((size_t)(c0 >> 4) * 8 + (k0 >> 5)) << 9) + lane * 8;
        short8 ah0 = *(const short8*)&Ahi[at];
        short8 al0 = *(const short8*)&Alo[at];
        short8 ah1 = *(const short8*)&Ahi[at + 4096];
        short8 al1 = *(const short8*)&Alo[at + 4096];
        short8 bh = *(const short8*)&Bhi[bt];
        short8 bl = *(const short8*)&Blo[bt];
        acc0 = __builtin_amdgcn_mfma_f32_16x16x32_bf16(ah0, bh, acc0, 0, 0, 0);
        acc0 = __builtin_amdgcn_mfma_f32_16x16x32_bf16(ah0, bl, acc0, 0, 0, 0);
        acc0 = __builtin_amdgcn_mfma_f32_16x16x32_bf16(al0, bh, acc0, 0, 0, 0);
        acc1 = __builtin_amdgcn_mfma_f32_16x16x32_bf16(ah1, bh, acc1, 0, 0, 0);
        acc1 = __builtin_amdgcn_mfma_f32_16x16x32_bf16(ah1, bl, acc1, 0, 0, 0);
        acc1 = __builtin_amdgcn_mfma_f32_16x16x32_bf16(al1, bh, acc1, 0, 0, 0);
    }
    int c = c0 + l16;
    float bs = bias[c];
    #pragma unroll
    for (int r = 0; r < 4; ++r) {
        int R0 = r0 + quad * 4 + r;
        out[(size_t)R0 * DIM + c] = acc0[r] + bs;
        out[(size_t)(R0 + 16) * DIM + c] = acc1[r] + bs;
    }
}

extern "C" void kernel_launch(void* const* d_in, const int* in_sizes, int n_in,
                              void* d_out, int out_size, void* d_ws, size_t ws_size,
                              hipStream_t stream)
{
    const float* x    = (const float*)d_in[0];
    const float* mask = (const float*)d_in[1];
    const float* ln_g = (const float*)d_in[2];
    const float* ln_b = (const float*)d_in[3];
    const float* Wq   = (const float*)d_in[4];
    const float* bq   = (const float*)d_in[5];
    const float* Wk   = (const float*)d_in[6];
    const float* bk   = (const float*)d_in[7];
    const float* Wv   = (const float*)d_in[8];
    const float* bv   = (const float*)d_in[9];
    const float* Wp   = (const float*)d_in[10];
    const float* bp   = (const float*)d_in[11];
    float* out = (float*)d_out;

    constexpr size_t SZ  = (size_t)M * DIM;          // 2359296
    constexpr size_t CSZ = (size_t)B * NH * CST;     // 2392064
    constexpr size_t WSZ = (size_t)DIM * DIM;        // 65536
    unsigned short* p = (unsigned short*)d_ws;
    unsigned short* xh = p;  p += SZ;
    unsigned short* xl = p;  p += SZ;
    unsigned short* qb = p;  p += SZ;
    unsigned short* kc = p;  p += CSZ;
    unsigned short* vc = p;  p += CSZ;
    unsigned short* ah = p;  p += SZ;   // attn out hi
    unsigned short* al = p;  p += SZ;   // attn out lo
    unsigned short* wth = p; p += 4 * WSZ;
    unsigned short* wtl = p; p += 4 * WSZ;
    float* po = (float*)p;                       // B*NH*2*N*DH fp32
    float* pl = po + (size_t)B * NH * 2 * N * DH;
    float* vm = pl + (size_t)B * NH * 2 * N;     // B*NH*32
    int* slotmap = (int*)(vm + (size_t)B * NH * 32);
    int* ncp = slotmap + (size_t)B * N;

    mask_scan<<<B, 256, 0, stream>>>(mask, slotmap, ncp);

    ln_kernel<<<M / 4, 256, 0, stream>>>(x, ln_g, ln_b, xh, xl);

    split_w<<<dim3(8, 8, 4), 256, 0, stream>>>(Wq, Wk, Wv, Wp, wth, wtl);

    gemm_qkv<<<dim3(576, 1, 3), 256, 0, stream>>>(
        xh, xl, wth, wtl, bq, bk, bv, slotmap, qb, kc, vc);

    hipMemsetAsync(vm, 0, (size_t)B * NH * 32 * sizeof(float), stream);
    vmsum_kernel<<<dim3(B * NH, 8), 256, 0, stream>>>(vc, ncp, vm);

    attn_kernel<<<dim3(N / 128, B * NH, 2), 256, 0, stream>>>(
        qb, kc, vc, ncp, po, pl);

    combine_kernel<<<(B * NH * N * 4) / 256, 256, 0, stream>>>(
        po, pl, vm, ncp, ah, al);

    gemm_p<<<dim3(DIM / 16, M / 128), 256, 0, stream>>>(
        ah, al, wth, wtl, bp, out);
}